// Round 6
// baseline (345.429 us; speedup 1.0000x reference)
//
#include <hip/hip_runtime.h>

typedef unsigned short u16;
typedef __attribute__((ext_vector_type(8))) short short8;
typedef __attribute__((ext_vector_type(4))) short short4v;
typedef __attribute__((ext_vector_type(4))) float floatx4;

// round-half-up bf16 (1 add + 1 shr); max error 0.5 ulp like RTNE (ties round up)
__device__ __forceinline__ u16 f2bf(float f) {
  return (u16)((__float_as_uint(f) + 0x8000u) >> 16);
}
__device__ __forceinline__ float bf2f(u16 v) {
  return __uint_as_float(((unsigned)v) << 16);
}
// pack two floats -> two bf16 in one u32: [hi16(b), hi16(a)]
__device__ __forceinline__ unsigned pack_bf2(float a, float b) {
  const unsigned ua = __float_as_uint(a) + 0x8000u;
  const unsigned ub = __float_as_uint(b) + 0x8000u;
  return __builtin_amdgcn_perm(ub, ua, 0x07060302);
}

#define GLD16(g, l) __builtin_amdgcn_global_load_lds( \
    (const __attribute__((address_space(1))) void*)(g), \
    (__attribute__((address_space(3))) void*)(l), 16, 0, 0)

// ---------------- prep: 4 weight transposes + rmsnorm(x,y), one launch ----------------
__global__ __launch_bounds__(256) void prep(const float* __restrict__ W0, u16* __restrict__ T0,
                                            const float* __restrict__ W1, u16* __restrict__ T1,
                                            const float* __restrict__ W2, u16* __restrict__ T2,
                                            const float* __restrict__ W3, u16* __restrict__ T3,
                                            const float* __restrict__ x, const float* __restrict__ scale_x,
                                            const float* __restrict__ y, const float* __restrict__ scale_y,
                                            u16* __restrict__ xm, u16* __restrict__ ym) {
  __shared__ float t[32][33];
  const int z = blockIdx.z;
  if (z < 4) {
    const float* in; u16* out; int K, N;
    switch (z) {
      case 0: in = W0; out = T0; K = 1536; N = 4608; break;
      case 1: in = W1; out = T1; K = 768;  N = 4608; break;
      case 2: in = W2; out = T2; K = 1536; N = 1536; break;
      default: in = W3; out = T3; K = 1536; N = 768; break;
    }
    const int n0 = blockIdx.x * 32, k0 = blockIdx.y * 32;
    if (n0 >= N || k0 >= K) return;
    const int tx = threadIdx.x, ty = threadIdx.y;   // 32 x 8
#pragma unroll
    for (int i = 0; i < 32; i += 8)
      t[ty + i][tx] = in[(size_t)(k0 + ty + i) * N + n0 + tx];
    __syncthreads();
#pragma unroll
    for (int i = 0; i < 32; i += 8)
      out[(size_t)(n0 + ty + i) * K + k0 + tx] = f2bf(t[tx][ty + i]);
  } else {
    const int row = blockIdx.y * 144 + blockIdx.x;
    if (row >= 2304) return;
    const int tid = threadIdx.y * 32 + threadIdx.x;
    const float* xr; const float* sc; u16* dst; int D;
    if (row < 2048) { D = 1536; xr = x + (size_t)row * D; sc = scale_x; dst = xm + (size_t)row * D; }
    else { D = 768; xr = y + (size_t)(row - 2048) * D; sc = scale_y; dst = ym + (size_t)(row - 2048) * D; }
    float ss = 0.f;
    for (int c = tid; c < D; c += 256) { float v = xr[c]; ss += v * v; }
    for (int off = 32; off > 0; off >>= 1) ss += __shfl_down(ss, off);
    __shared__ float red[4];
    if ((tid & 63) == 0) red[tid >> 6] = ss;
    __syncthreads();
    const float tot = red[0] + red[1] + red[2] + red[3];
    const float r = rsqrtf(tot / (float)D + 1e-6f);
    for (int c = tid; c < D; c += 256)
      dst[c] = f2bf(xr[c] * r * (1.0f + sc[c]));
  }
}

// ---------------- dual bf16 MFMA GEMM (global_load_lds staging); z picks problem ----------------
template <bool BOUT>
__global__ __launch_bounds__(256) void gemm2(const u16* __restrict__ A0, const u16* __restrict__ BT0,
                                             const float* __restrict__ bias0, void* __restrict__ C0,
                                             int M0, int N0, int K0,
                                             const u16* __restrict__ A1, const u16* __restrict__ BT1,
                                             const float* __restrict__ bias1, void* __restrict__ C1,
                                             int M1, int N1, int K1) {
  const u16 *A, *BT; const float* bias; void* Cout; int M, N, K;
  if (blockIdx.z == 0) { A = A0; BT = BT0; bias = bias0; Cout = C0; M = M0; N = N0; K = K0; }
  else { A = A1; BT = BT1; bias = bias1; Cout = C1; M = M1; N = N1; K = K1; }
  const int bm = blockIdx.y * 128, bn = blockIdx.x * 128;
  if (bm >= M || bn >= N) return;

  __shared__ __align__(16) u16 As[128 * 32];
  __shared__ __align__(16) u16 Bs[128 * 32];
  const int tid = threadIdx.x;
  const int lane = tid & 63, wave = tid >> 6;
  const int wm = (wave & 1) * 64, wn = (wave >> 1) * 64;
  const int row16 = lane & 15, quad = lane >> 4;

  floatx4 acc[4][4] = {};
  const int r0 = lane >> 2, c4 = (lane & 3) * 8;
  const u16* Ag0 = A + (size_t)(bm + wave * 16 + r0) * K + c4;
  const u16* Ag1 = A + (size_t)(bm + (wave + 4) * 16 + r0) * K + c4;
  const u16* Bg0 = BT + (size_t)(bn + wave * 16 + r0) * K + c4;
  const u16* Bg1 = BT + (size_t)(bn + (wave + 4) * 16 + r0) * K + c4;
  u16* As0 = As + wave * 512; u16* As1 = As + (wave + 4) * 512;
  u16* Bs0 = Bs + wave * 512; u16* Bs1 = Bs + (wave + 4) * 512;

  for (int k0 = 0; k0 < K; k0 += 32) {
    GLD16(Ag0 + k0, As0);
    GLD16(Ag1 + k0, As1);
    GLD16(Bg0 + k0, Bs0);
    GLD16(Bg1 + k0, Bs1);
    __syncthreads();
    short8 af[4], bf[4];
#pragma unroll
    for (int i = 0; i < 4; i++) {
      af[i] = *(const short8*)&As[(wm + i * 16 + row16) * 32 + quad * 8];
      bf[i] = *(const short8*)&Bs[(wn + i * 16 + row16) * 32 + quad * 8];
    }
#pragma unroll
    for (int mi = 0; mi < 4; mi++)
#pragma unroll
      for (int ni = 0; ni < 4; ni++)
        acc[mi][ni] = __builtin_amdgcn_mfma_f32_16x16x32_bf16(af[mi], bf[ni], acc[mi][ni], 0, 0, 0);
    __syncthreads();
  }
#pragma unroll
  for (int mi = 0; mi < 4; mi++) {
#pragma unroll
    for (int ni = 0; ni < 4; ni++) {
      const int col = bn + wn + ni * 16 + row16;
      const float b = bias[col];
      const int row0 = bm + wm + mi * 16 + quad * 4;
#pragma unroll
      for (int r = 0; r < 4; r++) {
        const float v = acc[mi][ni][r] + b;
        if constexpr (BOUT)
          ((u16*)Cout)[(size_t)(row0 + r) * N + col] = f2bf(v);
        else
          ((float*)Cout)[(size_t)(row0 + r) * N + col] = v;
      }
    }
  }
}

// ---------------- qkv_post fused: q/k RMSNorm + RoPE + V transpose, block = 32 seq x 1 head ----
// Emits Q,K in (H,S,D) bf16 and V directly transposed (H,D,S). Q folded with 1/sqrt(D)*log2(e).
__global__ __launch_bounds__(256) void qkv_post(const u16* __restrict__ qkvx,
                                                const u16* __restrict__ qkvy,
                                                const float* __restrict__ qnwx, const float* __restrict__ knwx,
                                                const float* __restrict__ qnwy, const float* __restrict__ knwy,
                                                const float* __restrict__ rcos, const float* __restrict__ rsin,
                                                u16* __restrict__ Q, u16* __restrict__ Kb, u16* __restrict__ Vt) {
  const int s0 = blockIdx.x * 32, h = blockIdx.y;
  const int tid = threadIdx.x;
  const int r = tid >> 3, j = tid & 7, d0 = j * 16;
  const int s = s0 + r;
  const bool isx = s0 < 2048;
  const u16* base = isx ? (qkvx + (size_t)s * 4608) : (qkvy + (size_t)(s - 2048) * 4608);

  __shared__ __align__(16) u16 Vtile[128][40];  // 40: 80B row stride keeps 16B alignment

  // load 16 contiguous d for q,k,v
  short8 q8a = *(const short8*)(base + h * 128 + d0);
  short8 q8b = *(const short8*)(base + h * 128 + d0 + 8);
  short8 k8a = *(const short8*)(base + 1536 + h * 128 + d0);
  short8 k8b = *(const short8*)(base + 1536 + h * 128 + d0 + 8);
  short8 v8a = *(const short8*)(base + 3072 + h * 128 + d0);
  short8 v8b = *(const short8*)(base + 3072 + h * 128 + d0 + 8);

  float qv[16], kv[16];
  float sq = 0.f, sk = 0.f;
#pragma unroll
  for (int i = 0; i < 8; i++) {
    qv[i] = bf2f((u16)q8a[i]); qv[8 + i] = bf2f((u16)q8b[i]);
    kv[i] = bf2f((u16)k8a[i]); kv[8 + i] = bf2f((u16)k8b[i]);
  }
#pragma unroll
  for (int i = 0; i < 16; i++) { sq += qv[i] * qv[i]; sk += kv[i] * kv[i]; }
  // reduce across the 8 lanes of this row (lanes are contiguous within a wave)
  sq += __shfl_xor(sq, 1); sq += __shfl_xor(sq, 2); sq += __shfl_xor(sq, 4);
  sk += __shfl_xor(sk, 1); sk += __shfl_xor(sk, 2); sk += __shfl_xor(sk, 4);
  const float rq = rsqrtf(sq * (1.f / 128.f) + 1e-5f);
  const float rk = rsqrtf(sk * (1.f / 128.f) + 1e-5f);

  const float* qw = isx ? qnwx : qnwy;
  const float* kw = isx ? knwx : knwy;
#pragma unroll
  for (int i = 0; i < 16; i++) {
    qv[i] *= rq * qw[d0 + i];
    kv[i] *= rk * kw[d0 + i];
  }
  if (isx) {
    const float* cp = rcos + ((size_t)s * 12 + h) * 64 + d0 / 2;
    const float* sp = rsin + ((size_t)s * 12 + h) * 64 + d0 / 2;
#pragma unroll
    for (int i = 0; i < 16; i += 2) {
      const float c = cp[i / 2], sn = sp[i / 2];
      const float qe = qv[i], qo = qv[i + 1];
      const float ke = kv[i], ko = kv[i + 1];
      qv[i] = qe * c - qo * sn; qv[i + 1] = qe * sn + qo * c;
      kv[i] = ke * c - ko * sn; kv[i + 1] = ke * sn + ko * c;
    }
  }
  short8 qo8[2], ko8[2];
#pragma unroll
  for (int half = 0; half < 2; half++)
#pragma unroll
    for (int i = 0; i < 8; i++) {
      qo8[half][i] = (short)f2bf(qv[half * 8 + i] * 0.12751737942f);  // (1/sqrt(128))*log2(e)
      ko8[half][i] = (short)f2bf(kv[half * 8 + i]);
    }
  const size_t o = ((size_t)h * 2304 + s) * 128 + d0;
  *(short8*)(Q + o) = qo8[0];  *(short8*)(Q + o + 8) = qo8[1];
  *(short8*)(Kb + o) = ko8[0]; *(short8*)(Kb + o + 8) = ko8[1];

  // V transpose through LDS: Vtile[d][r]
#pragma unroll
  for (int i = 0; i < 8; i++) {
    Vtile[d0 + i][r] = (u16)v8a[i];
    Vtile[d0 + 8 + i][r] = (u16)v8b[i];
  }
  __syncthreads();
  const int d = tid >> 1, sh = (tid & 1) * 16;
  short8 va = *(const short8*)&Vtile[d][sh];
  short8 vb = *(const short8*)&Vtile[d][sh + 8];
  u16* vdst = Vt + ((size_t)h * 128 + d) * 2304 + s0 + sh;
  *(short8*)vdst = va;
  *(short8*)(vdst + 8) = vb;
}

// ---------------- flash attention: 128 q/block (32/wave in 2 groups), 64-key tiles, 6 splits ----
// Grid (18 q-tiles, 12 heads, 6 splits), 384 keys/split. LDS 48KB -> 3 blocks/CU.
__global__ __launch_bounds__(256, 3) void attn(const u16* __restrict__ Q, const u16* __restrict__ Kb,
                                               const u16* __restrict__ Vt,
                                               u16* __restrict__ Opart,
                                               float* __restrict__ Mp, float* __restrict__ Lp) {
  const int h = blockIdx.y, split = blockIdx.z;
  const int q0 = blockIdx.x * 128;
  const int tid = threadIdx.x, lane = tid & 63, wave = tid >> 6;
  const int row16 = lane & 15, quad = lane >> 4;
  const u16* Qh = Q + (size_t)h * 2304 * 128;
  const u16* Kh = Kb + (size_t)h * 2304 * 128;
  const u16* Vh = Vt + (size_t)h * 128 * 2304;

  __shared__ __align__(16) u16 Ks[64 * 128];    // swizzled
  __shared__ __align__(16) u16 Vs[128 * 64];    // swizzled
  __shared__ __align__(16) u16 Ps[4][32 * 64];  // per-wave P, 32 q rows

  short8 qf[2][4];
#pragma unroll
  for (int g = 0; g < 2; g++) {
    const u16* qrow = Qh + (size_t)(q0 + wave * 32 + g * 16 + row16) * 128;
#pragma unroll
    for (int kk = 0; kk < 4; kk++) qf[g][kk] = *(const short8*)(qrow + kk * 32 + quad * 8);
  }
  floatx4 oacc[8][2] = {};
  float m_i[2] = {-1e30f, -1e30f}, l_i[2] = {0.f, 0.f};

  int krow[4], kcol[4], vrow[4], vcol[4];
#pragma unroll
  for (int i = 0; i < 4; i++) {
    const int jj = i * 4 + wave;
    krow[i] = jj * 4 + (lane >> 4);
    kcol[i] = ((lane & 15) ^ (krow[i] & 7)) * 8;
    vrow[i] = jj * 8 + (lane >> 3);
    vcol[i] = ((lane & 7) ^ (vrow[i] & 7)) * 8;
  }
  const int sw = row16 & 7;
  const int kbeg = split * 384, kend = kbeg + 384;

  for (int kt = kbeg; kt < kend; kt += 64) {
    __syncthreads();
#pragma unroll
    for (int i = 0; i < 4; i++) {
      GLD16(Kh + (size_t)(kt + krow[i]) * 128 + kcol[i], Ks + (i * 4 + wave) * 512);
      GLD16(Vh + (size_t)vrow[i] * 2304 + kt + vcol[i], Vs + (i * 4 + wave) * 512);
    }
    __syncthreads();

    // S^T: sacc[mk][g]: keys mk*16+quad*4+r, q-col = g*16+row16. kfrag shared across g.
    floatx4 sacc[4][2] = {};
#pragma unroll
    for (int mk = 0; mk < 4; mk++) {
#pragma unroll
      for (int kk = 0; kk < 4; kk++) {
        const int c = (4 * kk + quad) ^ sw;
        const short8 kfrag = *(const short8*)&Ks[(mk * 16 + row16) * 128 + c * 8];
        sacc[mk][0] = __builtin_amdgcn_mfma_f32_16x16x32_bf16(kfrag, qf[0][kk], sacc[mk][0], 0, 0, 0);
        sacc[mk][1] = __builtin_amdgcn_mfma_f32_16x16x32_bf16(kfrag, qf[1][kk], sacc[mk][1], 0, 0, 0);
      }
    }
    float mnew[2];
#pragma unroll
    for (int g = 0; g < 2; g++) {
      float mx = sacc[0][g][0];
#pragma unroll
      for (int mk = 0; mk < 4; mk++)
#pragma unroll
        for (int r = 0; r < 4; r++) mx = fmaxf(mx, sacc[mk][g][r]);
      mx = fmaxf(mx, __shfl_xor(mx, 16));
      mx = fmaxf(mx, __shfl_xor(mx, 32));
      mnew[g] = fmaxf(m_i[g], mx);
    }
    if (__any(mnew[0] > m_i[0] || mnew[1] > m_i[1])) {
      const float al0 = exp2f(m_i[0] - mnew[0]);
      const float al1 = exp2f(m_i[1] - mnew[1]);
      m_i[0] = mnew[0]; m_i[1] = mnew[1];
      float a[4][2];
#pragma unroll
      for (int r = 0; r < 4; r++) {
        a[r][0] = __shfl(al0, quad * 4 + r);
        a[r][1] = __shfl(al1, quad * 4 + r);
      }
#pragma unroll
      for (int nd = 0; nd < 8; nd++)
#pragma unroll
        for (int g = 0; g < 2; g++) {
          oacc[nd][g][0] *= a[0][g]; oacc[nd][g][1] *= a[1][g];
          oacc[nd][g][2] *= a[2][g]; oacc[nd][g][3] *= a[3][g];
        }
      l_i[0] *= al0; l_i[1] *= al1;
    }
#pragma unroll
    for (int g = 0; g < 2; g++) {
      float s = 0.f;
#pragma unroll
      for (int mk = 0; mk < 4; mk++) {
#pragma unroll
        for (int r = 0; r < 4; r++) {
          const float p = exp2f(sacc[mk][g][r] - m_i[g]);
          sacc[mk][g][r] = p;
          s += p;
        }
      }
      s += __shfl_xor(s, 16);
      s += __shfl_xor(s, 32);
      l_i[g] += s;
    }
    // P -> per-wave swizzled LDS rows (q = g*16+row16), conflict-free b64 writes
#pragma unroll
    for (int g = 0; g < 2; g++)
#pragma unroll
      for (int mk = 0; mk < 4; mk++) {
        const int subp = (4 * mk + quad) ^ (sw << 1);
        uint2 pk;
        pk.x = pack_bf2(sacc[mk][g][0], sacc[mk][g][1]);
        pk.y = pack_bf2(sacc[mk][g][2], sacc[mk][g][3]);
        *(uint2*)&Ps[wave][(g * 16 + row16) * 64 + subp * 4] = pk;
      }
    const int pc0 = quad ^ sw, pc1 = (4 + quad) ^ sw;
    short8 pf[2][2];
#pragma unroll
    for (int g = 0; g < 2; g++) {
      pf[g][0] = *(const short8*)&Ps[wave][(g * 16 + row16) * 64 + pc0 * 8];
      pf[g][1] = *(const short8*)&Ps[wave][(g * 16 + row16) * 64 + pc1 * 8];
    }
#pragma unroll
    for (int nd = 0; nd < 8; nd++) {
      const short8 vf0 = *(const short8*)&Vs[(nd * 16 + row16) * 64 + pc0 * 8];
      const short8 vf1 = *(const short8*)&Vs[(nd * 16 + row16) * 64 + pc1 * 8];
#pragma unroll
      for (int g = 0; g < 2; g++) {
        oacc[nd][g] = __builtin_amdgcn_mfma_f32_16x16x32_bf16(pf[g][0], vf0, oacc[nd][g], 0, 0, 0);
        oacc[nd][g] = __builtin_amdgcn_mfma_f32_16x16x32_bf16(pf[g][1], vf1, oacc[nd][g], 0, 0, 0);
      }
    }
  }
  const size_t base = (size_t)(split * 12 + h) * 2304 + q0 + wave * 32;
#pragma unroll
  for (int nd = 0; nd < 8; nd++)
#pragma unroll
    for (int g = 0; g < 2; g++)
#pragma unroll
      for (int r = 0; r < 4; r++)
        Opart[(base + g * 16 + quad * 4 + r) * 128 + nd * 16 + row16] = f2bf(oacc[nd][g][r]);
  if (lane < 16) {
    Mp[base + lane] = m_i[0];      Lp[base + lane] = l_i[0];
    Mp[base + 16 + lane] = m_i[1]; Lp[base + 16 + lane] = l_i[1];
  }
}

// ---------------- combine 6 splits (bf16 partials) -> attnout bf16 (S, 1536) ----------------
__global__ __launch_bounds__(256) void attn_combine(const u16* __restrict__ Opart,
                                                    const float* __restrict__ Mp,
                                                    const float* __restrict__ Lp,
                                                    u16* __restrict__ attnout) {
  const int idx = blockIdx.x * 256 + threadIdx.x;   // one per 8 output elems
  const int dd = (idx & 15) * 8;
  const int hq = idx >> 4;
  const int h = hq % 12, q = hq / 12;
  size_t b[6]; float ms[6], ls[6];
  float m = -1e30f;
#pragma unroll
  for (int s = 0; s < 6; s++) {
    b[s] = (size_t)(s * 12 + h) * 2304 + q;
    ms[s] = Mp[b[s]]; ls[s] = Lp[b[s]];
    m = fmaxf(m, ms[s]);
  }
  float w[6], denom = 0.f;
#pragma unroll
  for (int s = 0; s < 6; s++) { w[s] = exp2f(ms[s] - m); denom += ls[s] * w[s]; }
  const float inv = 1.0f / denom;
  float acc[8] = {};
#pragma unroll
  for (int s = 0; s < 6; s++) {
    const short8 o = *(const short8*)&Opart[b[s] * 128 + dd];
#pragma unroll
    for (int i = 0; i < 8; i++) acc[i] += bf2f((u16)o[i]) * w[s];
  }
  short8 outv;
#pragma unroll
  for (int i = 0; i < 8; i++) outv[i] = (short)f2bf(acc[i] * inv);
  *(short8*)&attnout[(size_t)idx * 8] = outv;
}

// ---------------- launch ----------------
extern "C" void kernel_launch(void* const* d_in, const int* in_sizes, int n_in,
                              void* d_out, int out_size, void* d_ws, size_t ws_size,
                              hipStream_t stream) {
  const float* x        = (const float*)d_in[0];
  const float* y        = (const float*)d_in[1];
  const float* scale_x  = (const float*)d_in[2];
  const float* scale_y  = (const float*)d_in[3];
  const float* rope_cos = (const float*)d_in[4];
  const float* rope_sin = (const float*)d_in[5];
  const float* Wqkv_x   = (const float*)d_in[6];
  const float* bqkv_x   = (const float*)d_in[7];
  const float* Wqkv_y   = (const float*)d_in[8];
  const float* bqkv_y   = (const float*)d_in[9];
  const float* qnwx     = (const float*)d_in[10];
  const float* knwx     = (const float*)d_in[11];
  const float* qnwy     = (const float*)d_in[12];
  const float* knwy     = (const float*)d_in[13];
  const float* Wproj_x  = (const float*)d_in[14];
  const float* bproj_x  = (const float*)d_in[15];
  const float* Wproj_y  = (const float*)d_in[16];
  const float* bproj_y  = (const float*)d_in[17];
  float* out = (float*)d_out;

  char* ws = (char*)d_ws;
  size_t off = 0;
  auto take = [&](size_t bytes) { char* p = ws + off; off += (bytes + 255) & ~(size_t)255; return p; };
  u16* WqkvxT  = (u16*)take((size_t)4608 * 1536 * 2);
  u16* WqkvyT  = (u16*)take((size_t)4608 * 768 * 2);
  u16* WprojxT = (u16*)take((size_t)1536 * 1536 * 2);
  u16* WprojyT = (u16*)take((size_t)768 * 1536 * 2);
  u16* xm      = (u16*)take((size_t)2048 * 1536 * 2);
  u16* ym      = (u16*)take((size_t)256 * 768 * 2);
  u16* qkvx    = (u16*)take((size_t)2048 * 4608 * 2);
  u16* qkvy    = (u16*)take((size_t)256 * 4608 * 2);
  u16* Qb      = (u16*)take((size_t)12 * 2304 * 128 * 2);
  u16* Kb      = (u16*)take((size_t)12 * 2304 * 128 * 2);
  u16* Vt      = (u16*)take((size_t)12 * 128 * 2304 * 2);
  u16* attnout = (u16*)take((size_t)2304 * 1536 * 2);
  u16* Opart   = (u16*)take((size_t)6 * 12 * 2304 * 128 * 2);
  float* Mp    = (float*)take((size_t)6 * 12 * 2304 * 4);
  float* Lp    = (float*)take((size_t)6 * 12 * 2304 * 4);

  prep<<<dim3(144, 48, 5), dim3(32, 8), 0, stream>>>(Wqkv_x, WqkvxT, Wqkv_y, WqkvyT,
                                                     Wproj_x, WprojxT, Wproj_y, WprojyT,
                                                     x, scale_x, y, scale_y, xm, ym);

  gemm2<true><<<dim3(36, 16, 2), 256, 0, stream>>>(xm, WqkvxT, bqkv_x, qkvx, 2048, 4608, 1536,
                                                   ym, WqkvyT, bqkv_y, qkvy, 256, 4608, 768);

  qkv_post<<<dim3(72, 12), 256, 0, stream>>>(qkvx, qkvy, qnwx, knwx, qnwy, knwy,
                                             rope_cos, rope_sin, Qb, Kb, Vt);

  attn<<<dim3(2304 / 128, 12, 6), 256, 0, stream>>>(Qb, Kb, Vt, Opart, Mp, Lp);
  attn_combine<<<(2304 * 1536 / 8) / 256, 256, 0, stream>>>(Opart, Mp, Lp, attnout);

  gemm2<false><<<dim3(12, 16, 2), 256, 0, stream>>>(attnout, WprojxT, bproj_x, out, 2048, 1536, 1536,
                                                    attnout + (size_t)2048 * 1536, WprojyT, bproj_y,
                                                    out + (size_t)2048 * 1536, 256, 768, 1536);
  (void)in_sizes; (void)n_in; (void)out_size; (void)ws_size;
}